// Round 4
// baseline (172.199 us; speedup 1.0000x reference)
//
#include <hip/hip_runtime.h>
#include <math.h>

#define N_PTS 50000
#define CCH   64
#define KP    15
#define NH    32
#define SIGMA 0.7f
#define BN_EPS 1e-5f
#define LEAKY 0.1f
#define QB    16
#define NT    (N_PTS / QB)      // 3125 query tiles
#define GMAIN 1024              // persistent k_main blocks (~3 tiles each)
#define STATS_BLOCKS 1024
#define SP4_BLOCKS 196
// cwP packed layout: uint word[(k*32 + c2)*17 + q] holds (bf16 ch 2c2) | (bf16 ch 2c2+1)<<16
// stride 17 words per c2 -> 17*c2 mod 32 bijective -> conflict-free ds_read_b32 in phase B
#define CW_KSTRIDE_B 2176   // 32*17*4 bytes per kernel-point block

typedef short bf16x8 __attribute__((ext_vector_type(8)));
typedef float floatx4 __attribute__((ext_vector_type(4)));

__device__ __forceinline__ unsigned short f2b(float f) {
    union { float f; unsigned u; } v; v.f = f;
    return (unsigned short)((v.u + 0x7FFFu + ((v.u >> 16) & 1u)) >> 16);  // RNE
}
__device__ __forceinline__ float b2f(unsigned short b) {
    union { unsigned u; float f; } v; v.u = ((unsigned)b) << 16;
    return v.f;
}
__device__ __forceinline__ float blo(unsigned u) {   // low bf16 of packed word
    union { unsigned u; float f; } v; v.u = u << 16;
    return v.f;
}
__device__ __forceinline__ float bhi(unsigned u) {   // high bf16 of packed word
    union { unsigned u; float f; } v; v.u = u & 0xFFFF0000u;
    return v.f;
}
// gfx950 packed f32->bf16 (RNE), one VALU op instead of 8
__device__ __forceinline__ unsigned cvtpk(float lo, float hi) {
    unsigned r;
    asm("v_cvt_pk_bf16_f32 %0, %1, %2" : "=v"(r) : "v"(lo), "v"(hi));
    return r;
}

// ---------- K1: blocks [0,STATS): h = sf@W1 -> hst (bf16) + BN sum/sumsq
//             + bf16 shadow copy of s_feats (sfb).
//             blocks [STATS, STATS+30): repack W2 into bf16 MFMA fragment order.
//             blocks [STATS+30, STATS+30+196): float4-pack s_pts -> sp4. ----------
__global__ __launch_bounds__(256) void k_prep(const float* __restrict__ sf,
                                              const float* __restrict__ W1,
                                              const float* __restrict__ W2,
                                              const float* __restrict__ s_pts,
                                              float* __restrict__ bn,
                                              unsigned short* __restrict__ hst,
                                              unsigned short* __restrict__ w2b,
                                              unsigned short* __restrict__ sfb,
                                              float* __restrict__ sp4) {
    int t = threadIdx.x;
    if (blockIdx.x >= STATS_BLOCKS + 30) {
        int g = (blockIdx.x - STATS_BLOCKS - 30) * 256 + t;
        if (g < N_PTS) {
            float4 v;
            v.x = s_pts[g * 3 + 0]; v.y = s_pts[g * 3 + 1];
            v.z = s_pts[g * 3 + 2]; v.w = 0.f;
            *(float4*)(sp4 + g * 4) = v;
        }
        return;
    }
    if (blockIdx.x >= STATS_BLOCKS) {
        // w2b[((tile*2+kstep)*64+lane)*8+j] = bf16(W2[k][n]),
        //   k = kstep*32 + (lane>>4)*8 + j, n = tile*16 + (lane&15)
        int g = (blockIdx.x - STATS_BLOCKS) * 256 + t;   // 7680 exactly
        int lane = g & 63, s = (g >> 6) & 1, tt = g >> 7;
        int col = lane & 15, quad = lane >> 4;
        int base = (s * 32 + quad * 8) * 960 + tt * 16 + col;
        ushort4 lo, hi;
        lo.x = f2b(W2[base + 0 * 960]); lo.y = f2b(W2[base + 1 * 960]);
        lo.z = f2b(W2[base + 2 * 960]); lo.w = f2b(W2[base + 3 * 960]);
        hi.x = f2b(W2[base + 4 * 960]); hi.y = f2b(W2[base + 5 * 960]);
        hi.z = f2b(W2[base + 6 * 960]); hi.w = f2b(W2[base + 7 * 960]);
        *(ushort4*)(w2b + g * 8)     = lo;
        *(ushort4*)(w2b + g * 8 + 4) = hi;
        return;
    }
    int c = t & 63, ml = t >> 6;
    float w1c[64];
    #pragma unroll
    for (int i = 0; i < 64; ++i) w1c[i] = W1[i * 64 + c];
    __shared__ float rows[4][64];
    float acc_s = 0.f, acc_q = 0.f;
    for (int m0 = blockIdx.x * 4; m0 < N_PTS; m0 += STATS_BLOCKS * 4) {
        __syncthreads();
        float v = sf[m0 * 64 + t];
        ((float*)rows)[t] = v;
        sfb[m0 * 64 + t] = f2b(v);             // bf16 shadow for phase-B gathers
        __syncthreads();
        float h = 0.f;
        #pragma unroll
        for (int i4 = 0; i4 < 16; ++i4) {
            float4 r = *(const float4*)&rows[ml][i4 * 4];
            h += r.x * w1c[i4 * 4] + r.y * w1c[i4 * 4 + 1]
               + r.z * w1c[i4 * 4 + 2] + r.w * w1c[i4 * 4 + 3];
        }
        acc_s += h;
        acc_q += h * h;
        hst[(m0 + ml) * 64 + c] = f2b(h);      // 128B/wave coalesced
    }
    __shared__ float red[2][256];
    red[0][t] = acc_s; red[1][t] = acc_q;
    __syncthreads();
    if (t < 64) {
        float s = red[0][t] + red[0][64 + t] + red[0][128 + t] + red[0][192 + t];
        float q = red[1][t] + red[1][64 + t] + red[1][128 + t] + red[1][192 + t];
        atomicAdd(&bn[t], s);
        atomicAdd(&bn[64 + t], q);
    }
}

// ---------- K2: fused main. PERSISTENT blocks: W2 fragments live in 120 VGPRs,
//             reused across ~3 query tiles; cross-tile prefetch of nb/hst/sp4. ----------
__global__ __launch_bounds__(256, 2) void k_main(
    const float* __restrict__ q_pts, const float* __restrict__ sp4,
    const unsigned short* __restrict__ sfb, const int* __restrict__ nb,
    const float* __restrict__ kpts, const float* __restrict__ gamma,
    const float* __restrict__ beta, const float* __restrict__ bn,
    const float* __restrict__ b2, const unsigned short* __restrict__ w2b,
    const unsigned short* __restrict__ hst, float* __restrict__ out) {

    __shared__ __align__(16) unsigned cwP[KP * 32 * 17];     // 32640 B packed cw words
    __shared__ float abS[128];                               // BN fold a[64], b[64]
    __shared__ int      nCnt[QB];
    __shared__ unsigned nPack[QB][NH];        // idx(0:15) | (k*2176 byte-off)(16:30)
    __shared__ float    nInf[QB][NH];

    int t = threadIdx.x;
    int lane = t & 63, wv = t >> 6;

    if (t < 64) {   // inline BN finalize (once per block)
        float mu  = bn[t] * (1.0f / N_PTS);
        float var = bn[64 + t] * (1.0f / N_PTS) - mu * mu;
        float a   = gamma[t] * rsqrtf(var + BN_EPS);
        abS[t]      = a;
        abS[64 + t] = beta[t] - mu * a;
    }

    // ---- W2 fragments: identical for every query tile -> registers, once ----
    bf16x8 Wf0[15], Wf1[15];
    #pragma unroll
    for (int i = 0; i < 15; ++i) {
        int tt = wv * 15 + i;
        Wf0[i] = *(const bf16x8*)(w2b + ((tt * 2 + 0) * 64 + lane) * 8);
        Wf1[i] = *(const bf16x8*)(w2b + ((tt * 2 + 1) * 64 + lane) * 8);
    }

    // ---- hoist kernel points (wave-uniform address -> scalar loads) ----
    float kpr[45];
    #pragma unroll
    for (int i = 0; i < 45; ++i) kpr[i] = kpts[i];

    int q0 = t >> 5, hh = t & 31;     // this thread's queries within a tile
    int q1 = q0 + 8;
    int row = lane & 15, half = lane >> 4;

    // ---- prologue prefetch for first tile ----
    int tile = blockIdx.x;
    int m0 = tile * QB;
    int idx0 = nb[(m0 + q0) * NH + hh];
    int idx1 = nb[(m0 + q1) * NH + hh];
    bf16x8 r0, r1;
    {
        const unsigned short* hrow = hst + (m0 + row) * 64 + half * 8;
        r0 = *(const bf16x8*)(hrow);
        r1 = *(const bf16x8*)(hrow + 32);
    }
    float qx0 = q_pts[(m0 + q0) * 3 + 0], qy0 = q_pts[(m0 + q0) * 3 + 1],
          qz0 = q_pts[(m0 + q0) * 3 + 2];
    float qx1 = q_pts[(m0 + q1) * 3 + 0], qy1 = q_pts[(m0 + q1) * 3 + 1],
          qz1 = q_pts[(m0 + q1) * 3 + 2];
    float4 sp0 = *(const float4*)(sp4 + idx0 * 4);
    float4 sp1 = *(const float4*)(sp4 + idx1 * 4);

    __syncthreads();    // abS visible

    while (true) {
        m0 = tile * QB;
        int ntile = tile + GMAIN;
        bool more = ntile < NT;

        // ---- phase 1: 1-NN kernel point + influence; ballot compaction.
        //      Non-kept lanes zero-fill the tail slots (branch-free phase B). ----
        unsigned pf0 = 0, pf1 = 0, pf2 = 0, pf3 = 0;
        {
            float px = sp0.x - qx0, py = sp0.y - qy0, pz = sp0.z - qz0;
            float best = 1e30f; int bi = 0;
            #pragma unroll
            for (int k = 0; k < KP; ++k) {
                float dx = px - kpr[k*3], dy = py - kpr[k*3+1], dz = pz - kpr[k*3+2];
                float d = dx*dx + dy*dy + dz*dz;
                if (d < best) { best = d; bi = k; }
            }
            float infl = 1.f - sqrtf(best) * (1.0f / SIGMA);
            bool keep = infl > 0.f;
            unsigned long long bal = __ballot(keep);
            unsigned mym = (unsigned)(bal >> (lane & 32));
            unsigned below = mym & ((1u << (lane & 31)) - 1u);
            int cnt = __popc(mym);
            int pos = keep ? __popc(below)
                           : cnt + ((lane & 31) - __popc(below));
            nPack[q0][pos] = keep ? ((unsigned)idx0 | ((unsigned)(bi * CW_KSTRIDE_B) << 16)) : 0u;
            nInf[q0][pos]  = keep ? infl : 0.f;
            if (keep) {
                const unsigned* rowp = (const unsigned*)(sfb + idx0 * 64);
                pf0 = rowp[0]; pf1 = rowp[16];
            }
            if ((lane & 31) == 0) nCnt[q0] = cnt;
        }
        {
            float px = sp1.x - qx1, py = sp1.y - qy1, pz = sp1.z - qz1;
            float best = 1e30f; int bi = 0;
            #pragma unroll
            for (int k = 0; k < KP; ++k) {
                float dx = px - kpr[k*3], dy = py - kpr[k*3+1], dz = pz - kpr[k*3+2];
                float d = dx*dx + dy*dy + dz*dz;
                if (d < best) { best = d; bi = k; }
            }
            float infl = 1.f - sqrtf(best) * (1.0f / SIGMA);
            bool keep = infl > 0.f;
            unsigned long long bal = __ballot(keep);
            unsigned mym = (unsigned)(bal >> (lane & 32));
            unsigned below = mym & ((1u << (lane & 31)) - 1u);
            int cnt = __popc(mym);
            int pos = keep ? __popc(below)
                           : cnt + ((lane & 31) - __popc(below));
            nPack[q1][pos] = keep ? ((unsigned)idx1 | ((unsigned)(bi * CW_KSTRIDE_B) << 16)) : 0u;
            nInf[q1][pos]  = keep ? infl : 0.f;
            if (keep) {
                const unsigned* rowp = (const unsigned*)(sfb + idx1 * 64);
                pf2 = rowp[0]; pf3 = rowp[16];
            }
            if ((lane & 31) == 0) nCnt[q1] = cnt;
        }

        // ---- fold BN + leaky into bf16 A-fragments ----
        bf16x8 a0, a1;
        {
            unsigned* A0 = (unsigned*)&a0;
            unsigned* A1 = (unsigned*)&a1;
            #pragma unroll
            for (int jw = 0; jw < 4; ++jw) {
                int c0 = half * 8 + jw * 2;
                float g00 = abS[c0]     * b2f((unsigned short)r0[jw*2])     + abS[64+c0];
                float g01 = abS[c0 + 1] * b2f((unsigned short)r0[jw*2 + 1]) + abS[64+c0+1];
                g00 = g00 > 0.f ? g00 : LEAKY * g00;
                g01 = g01 > 0.f ? g01 : LEAKY * g01;
                A0[jw] = cvtpk(g00, g01);
                int c1 = 32 + c0;
                float g10 = abS[c1]     * b2f((unsigned short)r1[jw*2])     + abS[64+c1];
                float g11 = abS[c1 + 1] * b2f((unsigned short)r1[jw*2 + 1]) + abS[64+c1+1];
                g10 = g10 > 0.f ? g10 : LEAKY * g10;
                g11 = g11 > 0.f ? g11 : LEAKY * g11;
                A1[jw] = cvtpk(g10, g11);
            }
        }

        // ---- issue next tile's independent loads (hidden under phase A) ----
        int idx0n, idx1n;
        bf16x8 r0n, r1n;
        float qx0n, qy0n, qz0n, qx1n, qy1n, qz1n;
        if (more) {
            int m0n = ntile * QB;
            idx0n = nb[(m0n + q0) * NH + hh];
            idx1n = nb[(m0n + q1) * NH + hh];
            const unsigned short* hrow = hst + (m0n + row) * 64 + half * 8;
            r0n = *(const bf16x8*)(hrow);
            r1n = *(const bf16x8*)(hrow + 32);
            qx0n = q_pts[(m0n + q0) * 3 + 0]; qy0n = q_pts[(m0n + q0) * 3 + 1];
            qz0n = q_pts[(m0n + q0) * 3 + 2];
            qx1n = q_pts[(m0n + q1) * 3 + 0]; qy1n = q_pts[(m0n + q1) * 3 + 1];
            qz1n = q_pts[(m0n + q1) * 3 + 2];
        }

        // ---- phase A: cw via SWAPPED MFMA from REGISTER W2 fragments ----
        {
            int colq = lane & 15, quad = lane >> 4;
            #pragma unroll
            for (int i = 0; i < 15; ++i) {
                int tt = wv * 15 + i;
                floatx4 acc = {0.f, 0.f, 0.f, 0.f};
                acc = __builtin_amdgcn_mfma_f32_16x16x32_bf16(Wf0[i], a0, acc, 0, 0, 0);
                acc = __builtin_amdgcn_mfma_f32_16x16x32_bf16(Wf1[i], a1, acc, 0, 0, 0);
                int n0 = tt * 16 + quad * 4;           // n for reg j=0 (multiple of 4)
                float4 bb = *(const float4*)&b2[n0];
                int k  = n0 >> 6;
                int c2 = (n0 & 63) >> 1;               // even; lane fills c2 and c2+1
                unsigned w0 = cvtpk(acc[0] + bb.x, acc[1] + bb.y);
                unsigned w1 = cvtpk(acc[2] + bb.z, acc[3] + bb.w);
                unsigned* dst = cwP + (k * 544 + c2 * 17 + colq);
                dst[0]  = w0;
                dst[17] = w1;
            }
        }

        // ---- dependent sp4 gathers for next tile (hidden under phase B) ----
        float4 sp0n, sp1n;
        if (more) {
            sp0n = *(const float4*)(sp4 + idx0n * 4);
            sp1n = *(const float4*)(sp4 + idx1n * 4);
        }

        // keep the sfb row prefetches alive until here
        asm volatile("" :: "v"(pf0), "v"(pf1), "v"(pf2), "v"(pf3));
        __syncthreads();

        // ---- phase B: half-wave per query of a pair; lane = r*32+c2 covers
        //      channels (2c2, 2c2+1). 4B gathers + conflict-free b32 cw reads. ----
        {
            int r = lane >> 5, c2 = lane & 31;
            const unsigned short* sfbC = sfb + c2 * 2;
            const unsigned char* cwB = (const unsigned char*)cwP;
            #pragma unroll
            for (int pp = 0; pp < 2; ++pp) {
                int qa = wv * 4 + pp * 2;
                int q  = qa + r;
                const unsigned* packRow = &nPack[q][0];
                const float*    infRow  = &nInf[q][0];
                const unsigned char* cwLane = cwB + (c2 * 17 + q) * 4;
                int nA = nCnt[qa], nB = nCnt[qa + 1];
                int na = nA > nB ? nA : nB;
                float acc0 = 0.f, acc1 = 0.f;
                for (int jj = 0; jj < na; jj += 4) {
                    uint4  pk = *(const uint4*)&packRow[jj];       // zero-padded: safe
                    float4 in = *(const float4*)&infRow[jj];
                    unsigned f0 = *(const unsigned*)(sfbC + (pk.x & 0xFFFFu) * 64);
                    unsigned f1 = *(const unsigned*)(sfbC + (pk.y & 0xFFFFu) * 64);
                    unsigned f2 = *(const unsigned*)(sfbC + (pk.z & 0xFFFFu) * 64);
                    unsigned f3 = *(const unsigned*)(sfbC + (pk.w & 0xFFFFu) * 64);
                    unsigned w0 = *(const unsigned*)(cwLane + (pk.x >> 16));
                    unsigned w1 = *(const unsigned*)(cwLane + (pk.y >> 16));
                    unsigned w2 = *(const unsigned*)(cwLane + (pk.z >> 16));
                    unsigned w3 = *(const unsigned*)(cwLane + (pk.w >> 16));
                    acc0 = fmaf(in.x * blo(f0), blo(w0), acc0);
                    acc1 = fmaf(in.x * bhi(f0), bhi(w0), acc1);
                    acc0 = fmaf(in.y * blo(f1), blo(w1), acc0);
                    acc1 = fmaf(in.y * bhi(f1), bhi(w1), acc1);
                    acc0 = fmaf(in.z * blo(f2), blo(w2), acc0);
                    acc1 = fmaf(in.z * bhi(f2), bhi(w2), acc1);
                    acc0 = fmaf(in.w * blo(f3), blo(w3), acc0);
                    acc1 = fmaf(in.w * bhi(f3), bhi(w3), acc1);
                }
                float2 o; o.x = acc0; o.y = acc1;
                *(float2*)&out[(m0 + q) * 64 + c2 * 2] = o;
            }
        }

        if (!more) break;
        // rotate prefetched state; barrier protects nPack/nInf/cwP reuse
        idx0 = idx0n; idx1 = idx1n;
        r0 = r0n; r1 = r1n;
        sp0 = sp0n; sp1 = sp1n;
        qx0 = qx0n; qy0 = qy0n; qz0 = qz0n;
        qx1 = qx1n; qy1 = qy1n; qz1 = qz1n;
        tile = ntile;
        __syncthreads();
    }
}

extern "C" void kernel_launch(void* const* d_in, const int* in_sizes, int n_in,
                              void* d_out, int out_size, void* d_ws, size_t ws_size,
                              hipStream_t stream) {
    const float* q_pts   = (const float*)d_in[0];
    const float* s_pts   = (const float*)d_in[1];
    const float* s_feats = (const float*)d_in[2];
    const int*   nb      = (const int*)d_in[3];
    const float* kpts    = (const float*)d_in[4];
    const float* W1      = (const float*)d_in[5];
    const float* gamma   = (const float*)d_in[6];
    const float* beta    = (const float*)d_in[7];
    const float* W2      = (const float*)d_in[8];
    const float* b2      = (const float*)d_in[9];
    float* out = (float*)d_out;

    float* ws = (float*)d_ws;
    float* bn = ws;                                        // 128 fp32
    unsigned short* w2b = (unsigned short*)(ws + 128);     // 61440 bf16 (122880 B)
    unsigned short* hst = w2b + 61440;                     // 50000*64 bf16 (6.4 MB)
    unsigned short* sfb = hst + N_PTS * CCH;               // 50000*64 bf16 (6.4 MB)
    float* sp4 = (float*)(sfb + N_PTS * CCH);              // 50000*4 fp32 (800 KB)

    hipMemsetAsync(bn, 0, 128 * sizeof(float), stream);
    k_prep<<<STATS_BLOCKS + 30 + SP4_BLOCKS, 256, 0, stream>>>(
        s_feats, W1, W2, s_pts, bn, hst, w2b, sfb, sp4);
    k_main<<<GMAIN, 256, 0, stream>>>(q_pts, sp4, sfb, nb, kpts,
                                      gamma, beta, bn, b2, w2b, hst, out);
}

// Round 5
// 152.696 us; speedup vs baseline: 1.1277x; 1.1277x over previous
//
#include <hip/hip_runtime.h>
#include <math.h>

#define N_PTS 50000
#define CCH   64
#define KP    15
#define NH    32
#define SIGMA 0.7f
#define BN_EPS 1e-5f
#define LEAKY 0.1f
#define QB    16
#define STATS_BLOCKS 1024
#define SP4_BLOCKS 196
// cwP packed layout: uint word[(k*32 + c2)*17 + q] holds (bf16 ch 2c2) | (bf16 ch 2c2+1)<<16
// stride 17 words per c2 -> 17*c2 mod 32 bijective -> conflict-free ds_read_b32 in phase B
#define CW_KSTRIDE_B 2176   // 32*17*4 bytes per kernel-point block

typedef short bf16x8 __attribute__((ext_vector_type(8)));
typedef float floatx4 __attribute__((ext_vector_type(4)));

__device__ __forceinline__ unsigned short f2b(float f) {
    union { float f; unsigned u; } v; v.f = f;
    return (unsigned short)((v.u + 0x7FFFu + ((v.u >> 16) & 1u)) >> 16);  // RNE
}
__device__ __forceinline__ float b2f(unsigned short b) {
    union { unsigned u; float f; } v; v.u = ((unsigned)b) << 16;
    return v.f;
}
__device__ __forceinline__ float blo(unsigned u) {   // low bf16 of packed word
    union { unsigned u; float f; } v; v.u = u << 16;
    return v.f;
}
__device__ __forceinline__ float bhi(unsigned u) {   // high bf16 of packed word
    union { unsigned u; float f; } v; v.u = u & 0xFFFF0000u;
    return v.f;
}
// gfx950 packed f32->bf16 (RNE), one VALU op instead of 8
__device__ __forceinline__ unsigned cvtpk(float lo, float hi) {
    unsigned r;
    asm("v_cvt_pk_bf16_f32 %0, %1, %2" : "=v"(r) : "v"(lo), "v"(hi));
    return r;
}

// ---------- K1: blocks [0,STATS): h = sf@W1 -> hst (bf16) + BN sum/sumsq
//             + bf16 shadow copy of s_feats (sfb). 16 rows / iteration:
//             4 KB staged per barrier pair, 3 iterations (was 1 KB x 13 -> latency-bound).
//             blocks [STATS, STATS+30): repack W2 into bf16 MFMA fragment order.
//             blocks [STATS+30, STATS+30+196): float4-pack s_pts -> sp4. ----------
__global__ __launch_bounds__(256) void k_prep(const float* __restrict__ sf,
                                              const float* __restrict__ W1,
                                              const float* __restrict__ W2,
                                              const float* __restrict__ s_pts,
                                              float* __restrict__ bn,
                                              unsigned short* __restrict__ hst,
                                              unsigned short* __restrict__ w2b,
                                              unsigned short* __restrict__ sfb,
                                              float* __restrict__ sp4) {
    int t = threadIdx.x;
    if (blockIdx.x >= STATS_BLOCKS + 30) {
        int g = (blockIdx.x - STATS_BLOCKS - 30) * 256 + t;
        if (g < N_PTS) {
            float4 v;
            v.x = s_pts[g * 3 + 0]; v.y = s_pts[g * 3 + 1];
            v.z = s_pts[g * 3 + 2]; v.w = 0.f;
            *(float4*)(sp4 + g * 4) = v;
        }
        return;
    }
    if (blockIdx.x >= STATS_BLOCKS) {
        // w2b[((tile*2+kstep)*64+lane)*8+j] = bf16(W2[k][n]),
        //   k = kstep*32 + (lane>>4)*8 + j, n = tile*16 + (lane&15)
        int g = (blockIdx.x - STATS_BLOCKS) * 256 + t;   // 7680 exactly
        int lane = g & 63, s = (g >> 6) & 1, tt = g >> 7;
        int col = lane & 15, quad = lane >> 4;
        int base = (s * 32 + quad * 8) * 960 + tt * 16 + col;
        ushort4 lo, hi;
        lo.x = f2b(W2[base + 0 * 960]); lo.y = f2b(W2[base + 1 * 960]);
        lo.z = f2b(W2[base + 2 * 960]); lo.w = f2b(W2[base + 3 * 960]);
        hi.x = f2b(W2[base + 4 * 960]); hi.y = f2b(W2[base + 5 * 960]);
        hi.z = f2b(W2[base + 6 * 960]); hi.w = f2b(W2[base + 7 * 960]);
        *(ushort4*)(w2b + g * 8)     = lo;
        *(ushort4*)(w2b + g * 8 + 4) = hi;
        return;
    }
    int c = t & 63, ml = t >> 6;
    float w1c[64];
    #pragma unroll
    for (int i = 0; i < 64; ++i) w1c[i] = W1[i * 64 + c];
    __shared__ float rows[16][64];     // 4 KB staged per iteration
    float acc_s = 0.f, acc_q = 0.f;
    for (int tile = blockIdx.x; tile < N_PTS / 16; tile += STATS_BLOCKS) {
        int m0 = tile * 16;
        __syncthreads();
        float4 v = *(const float4*)(sf + m0 * 64 + t * 4);
        ((float4*)rows)[t] = v;
        ushort4 s4;
        s4.x = f2b(v.x); s4.y = f2b(v.y); s4.z = f2b(v.z); s4.w = f2b(v.w);
        *(ushort4*)(sfb + m0 * 64 + t * 4) = s4;    // bf16 shadow, 8B/lane coalesced
        __syncthreads();
        #pragma unroll
        for (int rr = 0; rr < 4; ++rr) {
            int r = ml + rr * 4;       // wave ml owns rows {ml, ml+4, ml+8, ml+12}
            float h = 0.f;
            #pragma unroll
            for (int i4 = 0; i4 < 16; ++i4) {
                float4 rv = *(const float4*)&rows[r][i4 * 4];   // broadcast read
                h += rv.x * w1c[i4 * 4] + rv.y * w1c[i4 * 4 + 1]
                   + rv.z * w1c[i4 * 4 + 2] + rv.w * w1c[i4 * 4 + 3];
            }
            acc_s += h;
            acc_q += h * h;
            hst[(m0 + r) * 64 + c] = f2b(h);        // 128B/wave coalesced
        }
    }
    __shared__ float red[2][256];
    red[0][t] = acc_s; red[1][t] = acc_q;
    __syncthreads();
    if (t < 64) {
        float s = red[0][t] + red[0][64 + t] + red[0][128 + t] + red[0][192 + t];
        float q = red[1][t] + red[1][64 + t] + red[1][128 + t] + red[1][192 + t];
        atomicAdd(&bn[t], s);
        atomicAdd(&bn[64 + t], q);
    }
}

// ---------- K2: fused main. 256 threads / 4 waves (proven round-3 shape;
//             persistent/register-W2 variant spilled at VGPR=128 and regressed). ----------
__global__ __launch_bounds__(256, 4) void k_main(
    const float* __restrict__ q_pts, const float* __restrict__ sp4,
    const unsigned short* __restrict__ sfb, const int* __restrict__ nb,
    const float* __restrict__ kpts, const float* __restrict__ gamma,
    const float* __restrict__ beta, const float* __restrict__ bn,
    const float* __restrict__ b2, const unsigned short* __restrict__ w2b,
    const unsigned short* __restrict__ hst, float* __restrict__ out) {

    __shared__ __align__(16) unsigned cwP[KP * 32 * 17];     // 32640 B packed cw words
    __shared__ float abS[128];                               // BN fold a[64], b[64]
    __shared__ int      nCnt[QB];
    __shared__ unsigned nPack[QB][NH];        // idx(0:15) | (k*2176 byte-off)(16:30)
    __shared__ float    nInf[QB][NH];

    int t = threadIdx.x;
    int lane = t & 63, wv = t >> 6;
    int m0 = blockIdx.x * QB;

    // ---- issue neighbor-index loads FIRST (longest dependent chain) ----
    int q0 = t >> 5, hh = t & 31;     // task 0: queries 0..7
    int q1 = q0 + 8;                  // task 1: queries 8..15
    int idx0 = nb[(m0 + q0) * NH + hh];
    int idx1 = nb[(m0 + q1) * NH + hh];

    if (t < 64) {   // inline BN finalize
        float mu  = bn[t] * (1.0f / N_PTS);
        float var = bn[64 + t] * (1.0f / N_PTS) - mu * mu;
        float a   = gamma[t] * rsqrtf(var + BN_EPS);
        abS[t]      = a;
        abS[64 + t] = beta[t] - mu * a;
    }
    ((unsigned*)nPack)[t]       = 0u;    // zero-pad for branch-free phase B
    ((unsigned*)nPack)[t + 256] = 0u;
    ((float*)nInf)[t]           = 0.f;
    ((float*)nInf)[t + 256]     = 0.f;

    // ---- issue A-fragment hst loads early; consumed after phase 1 ----
    int row = lane & 15, half = lane >> 4;
    bf16x8 r0, r1;
    {
        const unsigned short* hrow = hst + (m0 + row) * 64 + half * 8;
        r0 = *(const bf16x8*)(hrow);        // c = half*8 + j
        r1 = *(const bf16x8*)(hrow + 32);   // c = 32 + half*8 + j
    }

    // ---- position gathers as soon as idx lands (float4-packed support pts) ----
    float4 sp0 = *(const float4*)(sp4 + idx0 * 4);
    float4 sp1 = *(const float4*)(sp4 + idx1 * 4);
    float qx0 = q_pts[(m0 + q0) * 3 + 0], qy0 = q_pts[(m0 + q0) * 3 + 1],
          qz0 = q_pts[(m0 + q0) * 3 + 2];
    float qx1 = q_pts[(m0 + q1) * 3 + 0], qy1 = q_pts[(m0 + q1) * 3 + 1],
          qz1 = q_pts[(m0 + q1) * 3 + 2];

    // ---- hoist kernel points (wave-uniform address -> scalar loads, regs) ----
    float kpr[45];
    #pragma unroll
    for (int i = 0; i < 45; ++i) kpr[i] = kpts[i];

    __syncthreads();    // abS visible to all waves

    // ---- phase 1: 1-NN kernel point + influence; ballot compaction.
    //      Each 32-lane half owns one query's 32 neighbors. Kept rows of sfb
    //      are prefetched (2 dwords cover the 128B row) and kept live until
    //      after phase A -> phase-B gathers become cache hits. ----
    unsigned pf0 = 0, pf1 = 0, pf2 = 0, pf3 = 0;
    {
        float px = sp0.x - qx0, py = sp0.y - qy0, pz = sp0.z - qz0;
        float best = 1e30f; int bi = 0;
        #pragma unroll
        for (int k = 0; k < KP; ++k) {
            float dx = px - kpr[k * 3], dy = py - kpr[k * 3 + 1], dz = pz - kpr[k * 3 + 2];
            float d = dx * dx + dy * dy + dz * dz;
            if (d < best) { best = d; bi = k; }
        }
        float infl = 1.f - sqrtf(best) * (1.0f / SIGMA);
        bool keep = infl > 0.f;
        unsigned long long bal = __ballot(keep);
        unsigned mym = (unsigned)(bal >> (lane & 32));
        int pos = __popc(mym & ((1u << (lane & 31)) - 1u));
        if (keep) {
            nPack[q0][pos] = (unsigned)idx0 | ((unsigned)(bi * CW_KSTRIDE_B) << 16);
            nInf[q0][pos]  = infl;
            const unsigned* rowp = (const unsigned*)(sfb + idx0 * 64);
            pf0 = rowp[0]; pf1 = rowp[16];
        }
        if ((lane & 31) == 0) nCnt[q0] = __popc(mym);
    }
    {
        float px = sp1.x - qx1, py = sp1.y - qy1, pz = sp1.z - qz1;
        float best = 1e30f; int bi = 0;
        #pragma unroll
        for (int k = 0; k < KP; ++k) {
            float dx = px - kpr[k * 3], dy = py - kpr[k * 3 + 1], dz = pz - kpr[k * 3 + 2];
            float d = dx * dx + dy * dy + dz * dz;
            if (d < best) { best = d; bi = k; }
        }
        float infl = 1.f - sqrtf(best) * (1.0f / SIGMA);
        bool keep = infl > 0.f;
        unsigned long long bal = __ballot(keep);
        unsigned mym = (unsigned)(bal >> (lane & 32));
        int pos = __popc(mym & ((1u << (lane & 31)) - 1u));
        if (keep) {
            nPack[q1][pos] = (unsigned)idx1 | ((unsigned)(bi * CW_KSTRIDE_B) << 16);
            nInf[q1][pos]  = infl;
            const unsigned* rowp = (const unsigned*)(sfb + idx1 * 64);
            pf2 = rowp[0]; pf3 = rowp[16];
        }
        if ((lane & 31) == 0) nCnt[q1] = __popc(mym);
    }

    // ---- fold BN + leaky into bf16 A-fragments (hst loads landed long ago) ----
    bf16x8 a0, a1;
    {
        unsigned* A0 = (unsigned*)&a0;
        unsigned* A1 = (unsigned*)&a1;
        #pragma unroll
        for (int jw = 0; jw < 4; ++jw) {
            int c0 = half * 8 + jw * 2;
            float g00 = abS[c0]     * b2f((unsigned short)r0[jw * 2])     + abS[64 + c0];
            float g01 = abS[c0 + 1] * b2f((unsigned short)r0[jw * 2 + 1]) + abS[64 + c0 + 1];
            g00 = g00 > 0.f ? g00 : LEAKY * g00;
            g01 = g01 > 0.f ? g01 : LEAKY * g01;
            A0[jw] = cvtpk(g00, g01);
            int c1 = 32 + c0;
            float g10 = abS[c1]     * b2f((unsigned short)r1[jw * 2])     + abS[64 + c1];
            float g11 = abS[c1 + 1] * b2f((unsigned short)r1[jw * 2 + 1]) + abS[64 + c1 + 1];
            g10 = g10 > 0.f ? g10 : LEAKY * g10;
            g11 = g11 > 0.f ? g11 : LEAKY * g11;
            A1[jw] = cvtpk(g10, g11);
        }
    }

    // ---- phase A: cw via SWAPPED MFMA -> D[n][q]; hand-pipelined in groups of 3
    //      tiles with next-group prefetch (L2 latency hides under MFMA+pack). ----
    {
        int colq = lane & 15, quad = lane >> 4;
        bf16x8 Lf[3], Ls[3], Mf[3], Ms[3];
        #pragma unroll
        for (int i = 0; i < 3; ++i) {
            int tt = wv * 15 + i;
            Lf[i] = *(const bf16x8*)(w2b + ((tt * 2 + 0) * 64 + lane) * 8);
            Ls[i] = *(const bf16x8*)(w2b + ((tt * 2 + 1) * 64 + lane) * 8);
        }
        #pragma unroll
        for (int g = 0; g < 5; ++g) {
            if (g < 4) {
                #pragma unroll
                for (int i = 0; i < 3; ++i) {
                    int tt = wv * 15 + (g + 1) * 3 + i;
                    Mf[i] = *(const bf16x8*)(w2b + ((tt * 2 + 0) * 64 + lane) * 8);
                    Ms[i] = *(const bf16x8*)(w2b + ((tt * 2 + 1) * 64 + lane) * 8);
                }
            }
            #pragma unroll
            for (int i = 0; i < 3; ++i) {
                int tt = wv * 15 + g * 3 + i;
                floatx4 acc = {0.f, 0.f, 0.f, 0.f};
                // swapped operands: arg0 = W2 frag (rows=n), arg1 = G frag (cols=q)
                acc = __builtin_amdgcn_mfma_f32_16x16x32_bf16(Lf[i], a0, acc, 0, 0, 0);
                acc = __builtin_amdgcn_mfma_f32_16x16x32_bf16(Ls[i], a1, acc, 0, 0, 0);
                int n0 = tt * 16 + quad * 4;           // n for reg j=0 (multiple of 4)
                float4 bb = *(const float4*)&b2[n0];
                int k  = n0 >> 6;
                int c2 = (n0 & 63) >> 1;               // even; lane fills c2 and c2+1
                unsigned w0 = cvtpk(acc[0] + bb.x, acc[1] + bb.y);
                unsigned w1 = cvtpk(acc[2] + bb.z, acc[3] + bb.w);
                unsigned* dst = cwP + (k * 544 + c2 * 17 + colq);
                dst[0]  = w0;
                dst[17] = w1;
            }
            if (g < 4) {
                #pragma unroll
                for (int i = 0; i < 3; ++i) { Lf[i] = Mf[i]; Ls[i] = Ms[i]; }
            }
        }
    }
    // keep the sfb row prefetches alive until here (waits happen before barrier)
    asm volatile("" :: "v"(pf0), "v"(pf1), "v"(pf2), "v"(pf3));
    __syncthreads();

    // ---- phase B: half-wave per query of a pair; lane = r*32+c2 covers channels
    //      (2c2, 2c2+1). 4B gathers + conflict-free b32 cw reads, 4-wide unroll. ----
    {
        int r = lane >> 5, c2 = lane & 31;
        const unsigned short* sfbC = sfb + c2 * 2;                 // + idx*64 ushorts
        const unsigned char* cwB = (const unsigned char*)cwP;
        #pragma unroll
        for (int pp = 0; pp < 2; ++pp) {
            int qa = wv * 4 + pp * 2;
            int q  = qa + r;                                       // this half's query
            const unsigned* packRow = &nPack[q][0];
            const float*    infRow  = &nInf[q][0];
            const unsigned char* cwLane = cwB + (c2 * 17 + q) * 4; // + k byte-off
            int nA = nCnt[qa], nB = nCnt[qa + 1];
            int na = nA > nB ? nA : nB;
            float acc0 = 0.f, acc1 = 0.f;
            for (int jj = 0; jj < na; jj += 4) {
                uint4  pk = *(const uint4*)&packRow[jj];           // zero-padded: safe
                float4 in = *(const float4*)&infRow[jj];
                unsigned f0 = *(const unsigned*)(sfbC + (pk.x & 0xFFFFu) * 64);
                unsigned f1 = *(const unsigned*)(sfbC + (pk.y & 0xFFFFu) * 64);
                unsigned f2 = *(const unsigned*)(sfbC + (pk.z & 0xFFFFu) * 64);
                unsigned f3 = *(const unsigned*)(sfbC + (pk.w & 0xFFFFu) * 64);
                unsigned w0 = *(const unsigned*)(cwLane + (pk.x >> 16));
                unsigned w1 = *(const unsigned*)(cwLane + (pk.y >> 16));
                unsigned w2 = *(const unsigned*)(cwLane + (pk.z >> 16));
                unsigned w3 = *(const unsigned*)(cwLane + (pk.w >> 16));
                acc0 = fmaf(in.x * blo(f0), blo(w0), acc0);
                acc1 = fmaf(in.x * bhi(f0), bhi(w0), acc1);
                acc0 = fmaf(in.y * blo(f1), blo(w1), acc0);
                acc1 = fmaf(in.y * bhi(f1), bhi(w1), acc1);
                acc0 = fmaf(in.z * blo(f2), blo(w2), acc0);
                acc1 = fmaf(in.z * bhi(f2), bhi(w2), acc1);
                acc0 = fmaf(in.w * blo(f3), blo(w3), acc0);
                acc1 = fmaf(in.w * bhi(f3), bhi(w3), acc1);
            }
            float2 o; o.x = acc0; o.y = acc1;
            *(float2*)&out[(m0 + q) * 64 + c2 * 2] = o;
        }
    }
}

extern "C" void kernel_launch(void* const* d_in, const int* in_sizes, int n_in,
                              void* d_out, int out_size, void* d_ws, size_t ws_size,
                              hipStream_t stream) {
    const float* q_pts   = (const float*)d_in[0];
    const float* s_pts   = (const float*)d_in[1];
    const float* s_feats = (const float*)d_in[2];
    const int*   nb      = (const int*)d_in[3];
    const float* kpts    = (const float*)d_in[4];
    const float* W1      = (const float*)d_in[5];
    const float* gamma   = (const float*)d_in[6];
    const float* beta    = (const float*)d_in[7];
    const float* W2      = (const float*)d_in[8];
    const float* b2      = (const float*)d_in[9];
    float* out = (float*)d_out;

    float* ws = (float*)d_ws;
    float* bn = ws;                                        // 128 fp32
    unsigned short* w2b = (unsigned short*)(ws + 128);     // 61440 bf16 (122880 B)
    unsigned short* hst = w2b + 61440;                     // 50000*64 bf16 (6.4 MB)
    unsigned short* sfb = hst + N_PTS * CCH;               // 50000*64 bf16 (6.4 MB)
    float* sp4 = (float*)(sfb + N_PTS * CCH);              // 50000*4 fp32 (800 KB)

    hipMemsetAsync(bn, 0, 128 * sizeof(float), stream);
    k_prep<<<STATS_BLOCKS + 30 + SP4_BLOCKS, 256, 0, stream>>>(
        s_feats, W1, W2, s_pts, bn, hst, w2b, sfb, sp4);
    k_main<<<N_PTS / QB, 256, 0, stream>>>(q_pts, sp4, sfb, nb, kpts,
                                           gamma, beta, bn, b2, w2b, hst, out);
}

// Round 7
// 152.442 us; speedup vs baseline: 1.1296x; 1.0017x over previous
//
#include <hip/hip_runtime.h>
#include <math.h>

#define N_PTS 50000
#define CCH   64
#define KP    15
#define NH    32
#define SIGMA 0.7f
#define BN_EPS 1e-5f
#define LEAKY 0.1f
#define QB    16
#define STATS_BLOCKS 1024
#define SP4_BLOCKS 196
// cwP packed layout: uint word[(k*32 + c2)*17 + q] holds (bf16 ch 2c2) | (bf16 ch 2c2+1)<<16
// stride 17 words per c2 -> 17*c2 mod 32 bijective -> conflict-free ds_read_b32 in phase B
#define CW_KSTRIDE_B 2176   // 32*17*4 bytes per kernel-point block

typedef short bf16x8 __attribute__((ext_vector_type(8)));
typedef float floatx4 __attribute__((ext_vector_type(4)));

__device__ __forceinline__ unsigned short f2b(float f) {
    union { float f; unsigned u; } v; v.f = f;
    return (unsigned short)((v.u + 0x7FFFu + ((v.u >> 16) & 1u)) >> 16);  // RNE
}
__device__ __forceinline__ float b2f(unsigned short b) {
    union { unsigned u; float f; } v; v.u = ((unsigned)b) << 16;
    return v.f;
}
__device__ __forceinline__ float blo(unsigned u) {   // low bf16 of packed word
    union { unsigned u; float f; } v; v.u = u << 16;
    return v.f;
}
__device__ __forceinline__ float bhi(unsigned u) {   // high bf16 of packed word
    union { unsigned u; float f; } v; v.u = u & 0xFFFF0000u;
    return v.f;
}
// gfx950 packed f32->bf16 (RNE), one VALU op instead of 8
__device__ __forceinline__ unsigned cvtpk(float lo, float hi) {
    unsigned r;
    asm("v_cvt_pk_bf16_f32 %0, %1, %2" : "=v"(r) : "v"(lo), "v"(hi));
    return r;
}

// ---------- K1: blocks [0,STATS): h = sf@W1 -> hst (bf16) + BN sum/sumsq
//             + bf16 shadow copy of s_feats (sfb). 16 rows / iteration.
//             blocks [STATS, STATS+30): repack W2 into bf16 MFMA fragment order.
//             blocks [STATS+30, +196): float4-pack s_pts -> sp4.
//             last block: kernel-point pack kpc4[k] = (x,y,z,|kp|^2/2). ----------
__global__ __launch_bounds__(256) void k_prep(const float* __restrict__ sf,
                                              const float* __restrict__ W1,
                                              const float* __restrict__ W2,
                                              const float* __restrict__ s_pts,
                                              const float* __restrict__ kpts,
                                              float* __restrict__ bn,
                                              unsigned short* __restrict__ hst,
                                              unsigned short* __restrict__ w2b,
                                              unsigned short* __restrict__ sfb,
                                              float* __restrict__ sp4,
                                              float* __restrict__ kpc4) {
    int t = threadIdx.x;
    if (blockIdx.x >= STATS_BLOCKS + 30 + SP4_BLOCKS) {
        if (t < KP) {
            float x = kpts[t * 3 + 0], y = kpts[t * 3 + 1], z = kpts[t * 3 + 2];
            float4 v; v.x = x; v.y = y; v.z = z; v.w = 0.5f * (x * x + y * y + z * z);
            *(float4*)(kpc4 + t * 4) = v;
        }
        return;
    }
    if (blockIdx.x >= STATS_BLOCKS + 30) {
        int g = (blockIdx.x - STATS_BLOCKS - 30) * 256 + t;
        if (g < N_PTS) {
            float4 v;
            v.x = s_pts[g * 3 + 0]; v.y = s_pts[g * 3 + 1];
            v.z = s_pts[g * 3 + 2]; v.w = 0.f;
            *(float4*)(sp4 + g * 4) = v;
        }
        return;
    }
    if (blockIdx.x >= STATS_BLOCKS) {
        // w2b[((tile*2+kstep)*64+lane)*8+j] = bf16(W2[k][n]),
        //   k = kstep*32 + (lane>>4)*8 + j, n = tile*16 + (lane&15)
        int g = (blockIdx.x - STATS_BLOCKS) * 256 + t;   // 7680 exactly
        int lane = g & 63, s = (g >> 6) & 1, tt = g >> 7;
        int col = lane & 15, quad = lane >> 4;
        int base = (s * 32 + quad * 8) * 960 + tt * 16 + col;
        ushort4 lo, hi;
        lo.x = f2b(W2[base + 0 * 960]); lo.y = f2b(W2[base + 1 * 960]);
        lo.z = f2b(W2[base + 2 * 960]); lo.w = f2b(W2[base + 3 * 960]);
        hi.x = f2b(W2[base + 4 * 960]); hi.y = f2b(W2[base + 5 * 960]);
        hi.z = f2b(W2[base + 6 * 960]); hi.w = f2b(W2[base + 7 * 960]);
        *(ushort4*)(w2b + g * 8)     = lo;
        *(ushort4*)(w2b + g * 8 + 4) = hi;
        return;
    }
    int c = t & 63, ml = t >> 6;
    float w1c[64];
    #pragma unroll
    for (int i = 0; i < 64; ++i) w1c[i] = W1[i * 64 + c];
    __shared__ float rows[16][64];     // 4 KB staged per iteration
    float acc_s = 0.f, acc_q = 0.f;
    for (int tile = blockIdx.x; tile < N_PTS / 16; tile += STATS_BLOCKS) {
        int m0 = tile * 16;
        __syncthreads();
        float4 v = *(const float4*)(sf + m0 * 64 + t * 4);
        ((float4*)rows)[t] = v;
        ushort4 s4;
        s4.x = f2b(v.x); s4.y = f2b(v.y); s4.z = f2b(v.z); s4.w = f2b(v.w);
        *(ushort4*)(sfb + m0 * 64 + t * 4) = s4;    // bf16 shadow, 8B/lane coalesced
        __syncthreads();
        #pragma unroll
        for (int rr = 0; rr < 4; ++rr) {
            int r = ml + rr * 4;       // wave ml owns rows {ml, ml+4, ml+8, ml+12}
            float h = 0.f;
            #pragma unroll
            for (int i4 = 0; i4 < 16; ++i4) {
                float4 rv = *(const float4*)&rows[r][i4 * 4];   // broadcast read
                h += rv.x * w1c[i4 * 4] + rv.y * w1c[i4 * 4 + 1]
                   + rv.z * w1c[i4 * 4 + 2] + rv.w * w1c[i4 * 4 + 3];
            }
            acc_s += h;
            acc_q += h * h;
            hst[(m0 + r) * 64 + c] = f2b(h);        // 128B/wave coalesced
        }
    }
    __shared__ float red[2][256];
    red[0][t] = acc_s; red[1][t] = acc_q;
    __syncthreads();
    if (t < 64) {
        float s = red[0][t] + red[0][64 + t] + red[0][128 + t] + red[0][192 + t];
        float q = red[1][t] + red[1][64 + t] + red[1][128 + t] + red[1][192 + t];
        atomicAdd(&bn[t], s);
        atomicAdd(&bn[64 + t], q);
    }
}

// ---------- K2: fused main. 256 threads / 4 waves (round-5 proven shape).
//             BISECT round-6: ONLY 6-op 1-NN (kpc4) + fmax-leaky re-applied;
//             phase A restored byte-identical to round 5 (b2 post-add). ----------
__global__ __launch_bounds__(256, 4) void k_main(
    const float* __restrict__ q_pts, const float* __restrict__ sp4,
    const unsigned short* __restrict__ sfb, const int* __restrict__ nb,
    const float* __restrict__ kpc4, const float* __restrict__ gamma,
    const float* __restrict__ beta, const float* __restrict__ bn,
    const float* __restrict__ b2, const unsigned short* __restrict__ w2b,
    const unsigned short* __restrict__ hst, float* __restrict__ out) {

    __shared__ __align__(16) unsigned cwP[KP * 32 * 17];     // 32640 B packed cw words
    __shared__ float abS[128];                               // BN fold a[64], b[64]
    __shared__ int      nCnt[QB];
    __shared__ unsigned nPack[QB][NH];        // idx(0:15) | (k*2176 byte-off)(16:30)
    __shared__ float    nInf[QB][NH];

    int t = threadIdx.x;
    int lane = t & 63, wv = t >> 6;
    int m0 = blockIdx.x * QB;

    // ---- issue neighbor-index loads FIRST (longest dependent chain) ----
    int q0 = t >> 5, hh = t & 31;     // task 0: queries 0..7
    int q1 = q0 + 8;                  // task 1: queries 8..15
    int idx0 = nb[(m0 + q0) * NH + hh];
    int idx1 = nb[(m0 + q1) * NH + hh];

    if (t < 64) {   // inline BN finalize
        float mu  = bn[t] * (1.0f / N_PTS);
        float var = bn[64 + t] * (1.0f / N_PTS) - mu * mu;
        float a   = gamma[t] * rsqrtf(var + BN_EPS);
        abS[t]      = a;
        abS[64 + t] = beta[t] - mu * a;
    }
    ((unsigned*)nPack)[t]       = 0u;    // zero-pad for branch-free phase B
    ((unsigned*)nPack)[t + 256] = 0u;
    ((float*)nInf)[t]           = 0.f;
    ((float*)nInf)[t + 256]     = 0.f;

    // ---- issue A-fragment hst loads early; consumed after phase 1 ----
    int row = lane & 15, half = lane >> 4;
    bf16x8 r0, r1;
    {
        const unsigned short* hrow = hst + (m0 + row) * 64 + half * 8;
        r0 = *(const bf16x8*)(hrow);        // c = half*8 + j
        r1 = *(const bf16x8*)(hrow + 32);   // c = 32 + half*8 + j
    }

    // ---- position gathers as soon as idx lands (float4-packed support pts) ----
    float4 sp0 = *(const float4*)(sp4 + idx0 * 4);
    float4 sp1 = *(const float4*)(sp4 + idx1 * 4);
    float qx0 = q_pts[(m0 + q0) * 3 + 0], qy0 = q_pts[(m0 + q0) * 3 + 1],
          qz0 = q_pts[(m0 + q0) * 3 + 2];
    float qx1 = q_pts[(m0 + q1) * 3 + 0], qy1 = q_pts[(m0 + q1) * 3 + 1],
          qz1 = q_pts[(m0 + q1) * 3 + 2];

    // ---- hoist packed kernel points (wave-uniform -> scalar s_load_dwordx4) ----
    float4 kq[KP];
    #pragma unroll
    for (int i = 0; i < KP; ++i) kq[i] = *(const float4*)(kpc4 + i * 4);

    __syncthreads();    // abS visible to all waves

    // ---- phase 1: 1-NN kernel point + influence; ballot compaction.
    //      d^2 = |p|^2 + 2*min_k(|kp|^2/2 - p.kp) -> 3 FMA + select per k.
    //      Kept sfb rows prefetched (2 dwords cover 128B row), live past phase A. ----
    unsigned pf0 = 0, pf1 = 0, pf2 = 0, pf3 = 0;
    {
        float px = sp0.x - qx0, py = sp0.y - qy0, pz = sp0.z - qz0;
        float pn = px * px + py * py + pz * pz;
        float best = 1e30f; int bi = 0;
        #pragma unroll
        for (int k = 0; k < KP; ++k) {
            float val = kq[k].w - (px * kq[k].x + py * kq[k].y + pz * kq[k].z);
            if (val < best) { best = val; bi = k; }
        }
        float d2 = fmaxf(fmaf(2.f, best, pn), 0.f);
        float infl = 1.f - sqrtf(d2) * (1.0f / SIGMA);
        bool keep = infl > 0.f;
        unsigned long long bal = __ballot(keep);
        unsigned mym = (unsigned)(bal >> (lane & 32));
        int pos = __popc(mym & ((1u << (lane & 31)) - 1u));
        if (keep) {
            nPack[q0][pos] = (unsigned)idx0 | ((unsigned)(bi * CW_KSTRIDE_B) << 16);
            nInf[q0][pos]  = infl;
            const unsigned* rowp = (const unsigned*)(sfb + idx0 * 64);
            pf0 = rowp[0]; pf1 = rowp[16];
        }
        if ((lane & 31) == 0) nCnt[q0] = __popc(mym);
    }
    {
        float px = sp1.x - qx1, py = sp1.y - qy1, pz = sp1.z - qz1;
        float pn = px * px + py * py + pz * pz;
        float best = 1e30f; int bi = 0;
        #pragma unroll
        for (int k = 0; k < KP; ++k) {
            float val = kq[k].w - (px * kq[k].x + py * kq[k].y + pz * kq[k].z);
            if (val < best) { best = val; bi = k; }
        }
        float d2 = fmaxf(fmaf(2.f, best, pn), 0.f);
        float infl = 1.f - sqrtf(d2) * (1.0f / SIGMA);
        bool keep = infl > 0.f;
        unsigned long long bal = __ballot(keep);
        unsigned mym = (unsigned)(bal >> (lane & 32));
        int pos = __popc(mym & ((1u << (lane & 31)) - 1u));
        if (keep) {
            nPack[q1][pos] = (unsigned)idx1 | ((unsigned)(bi * CW_KSTRIDE_B) << 16);
            nInf[q1][pos]  = infl;
            const unsigned* rowp = (const unsigned*)(sfb + idx1 * 64);
            pf2 = rowp[0]; pf3 = rowp[16];
        }
        if ((lane & 31) == 0) nCnt[q1] = __popc(mym);
    }

    // ---- fold BN + leaky into bf16 A-fragments (leaky = max(g, 0.1g)) ----
    bf16x8 a0, a1;
    {
        unsigned* A0 = (unsigned*)&a0;
        unsigned* A1 = (unsigned*)&a1;
        #pragma unroll
        for (int jw = 0; jw < 4; ++jw) {
            int c0 = half * 8 + jw * 2;
            float g00 = abS[c0]     * b2f((unsigned short)r0[jw * 2])     + abS[64 + c0];
            float g01 = abS[c0 + 1] * b2f((unsigned short)r0[jw * 2 + 1]) + abS[64 + c0 + 1];
            g00 = fmaxf(g00, LEAKY * g00);
            g01 = fmaxf(g01, LEAKY * g01);
            A0[jw] = cvtpk(g00, g01);
            int c1 = 32 + c0;
            float g10 = abS[c1]     * b2f((unsigned short)r1[jw * 2])     + abS[64 + c1];
            float g11 = abS[c1 + 1] * b2f((unsigned short)r1[jw * 2 + 1]) + abS[64 + c1 + 1];
            g10 = fmaxf(g10, LEAKY * g10);
            g11 = fmaxf(g11, LEAKY * g11);
            A1[jw] = cvtpk(g10, g11);
        }
    }

    // ---- phase A: cw via SWAPPED MFMA -> D[n][q]; hand-pipelined in groups of 3
    //      tiles with next-group prefetch (round-5 form: b2 added after MFMA). ----
    {
        int colq = lane & 15, quad = lane >> 4;
        bf16x8 Lf[3], Ls[3], Mf[3], Ms[3];
        #pragma unroll
        for (int i = 0; i < 3; ++i) {
            int tt = wv * 15 + i;
            Lf[i] = *(const bf16x8*)(w2b + ((tt * 2 + 0) * 64 + lane) * 8);
            Ls[i] = *(const bf16x8*)(w2b + ((tt * 2 + 1) * 64 + lane) * 8);
        }
        #pragma unroll
        for (int g = 0; g < 5; ++g) {
            if (g < 4) {
                #pragma unroll
                for (int i = 0; i < 3; ++i) {
                    int tt = wv * 15 + (g + 1) * 3 + i;
                    Mf[i] = *(const bf16x8*)(w2b + ((tt * 2 + 0) * 64 + lane) * 8);
                    Ms[i] = *(const bf16x8*)(w2b + ((tt * 2 + 1) * 64 + lane) * 8);
                }
            }
            #pragma unroll
            for (int i = 0; i < 3; ++i) {
                int tt = wv * 15 + g * 3 + i;
                floatx4 acc = {0.f, 0.f, 0.f, 0.f};
                // swapped operands: arg0 = W2 frag (rows=n), arg1 = G frag (cols=q)
                acc = __builtin_amdgcn_mfma_f32_16x16x32_bf16(Lf[i], a0, acc, 0, 0, 0);
                acc = __builtin_amdgcn_mfma_f32_16x16x32_bf16(Ls[i], a1, acc, 0, 0, 0);
                int n0 = tt * 16 + quad * 4;           // n for reg j=0 (multiple of 4)
                float4 bb = *(const float4*)&b2[n0];
                int k  = n0 >> 6;
                int c2 = (n0 & 63) >> 1;               // even; lane fills c2 and c2+1
                unsigned w0 = cvtpk(acc[0] + bb.x, acc[1] + bb.y);
                unsigned w1 = cvtpk(acc[2] + bb.z, acc[3] + bb.w);
                unsigned* dst = cwP + (k * 544 + c2 * 17 + colq);
                dst[0]  = w0;
                dst[17] = w1;
            }
            if (g < 4) {
                #pragma unroll
                for (int i = 0; i < 3; ++i) { Lf[i] = Mf[i]; Ls[i] = Ms[i]; }
            }
        }
    }
    // keep the sfb row prefetches alive until here (waits happen before barrier)
    asm volatile("" :: "v"(pf0), "v"(pf1), "v"(pf2), "v"(pf3));
    __syncthreads();

    // ---- phase B: half-wave per query of a pair; lane = r*32+c2 covers channels
    //      (2c2, 2c2+1). 4B gathers + conflict-free b32 cw reads, 4-wide unroll. ----
    {
        int r = lane >> 5, c2 = lane & 31;
        const unsigned short* sfbC = sfb + c2 * 2;                 // + idx*64 ushorts
        const unsigned char* cwB = (const unsigned char*)cwP;
        #pragma unroll
        for (int pp = 0; pp < 2; ++pp) {
            int qa = wv * 4 + pp * 2;
            int q  = qa + r;                                       // this half's query
            const unsigned* packRow = &nPack[q][0];
            const float*    infRow  = &nInf[q][0];
            const unsigned char* cwLane = cwB + (c2 * 17 + q) * 4; // + k byte-off
            int nA = nCnt[qa], nB = nCnt[qa + 1];
            int na = nA > nB ? nA : nB;
            float acc0 = 0.f, acc1 = 0.f;
            for (int jj = 0; jj < na; jj += 4) {
                uint4  pk = *(const uint4*)&packRow[jj];           // zero-padded: safe
                float4 in = *(const float4*)&infRow[jj];
                unsigned f0 = *(const unsigned*)(sfbC + (pk.x & 0xFFFFu) * 64);
                unsigned f1 = *(const unsigned*)(sfbC + (pk.y & 0xFFFFu) * 64);
                unsigned f2 = *(const unsigned*)(sfbC + (pk.z & 0xFFFFu) * 64);
                unsigned f3 = *(const unsigned*)(sfbC + (pk.w & 0xFFFFu) * 64);
                unsigned w0 = *(const unsigned*)(cwLane + (pk.x >> 16));
                unsigned w1 = *(const unsigned*)(cwLane + (pk.y >> 16));
                unsigned w2 = *(const unsigned*)(cwLane + (pk.z >> 16));
                unsigned w3 = *(const unsigned*)(cwLane + (pk.w >> 16));
                acc0 = fmaf(in.x * blo(f0), blo(w0), acc0);
                acc1 = fmaf(in.x * bhi(f0), bhi(w0), acc1);
                acc0 = fmaf(in.y * blo(f1), blo(w1), acc0);
                acc1 = fmaf(in.y * bhi(f1), bhi(w1), acc1);
                acc0 = fmaf(in.z * blo(f2), blo(w2), acc0);
                acc1 = fmaf(in.z * bhi(f2), bhi(w2), acc1);
                acc0 = fmaf(in.w * blo(f3), blo(w3), acc0);
                acc1 = fmaf(in.w * bhi(f3), bhi(w3), acc1);
            }
            float2 o; o.x = acc0; o.y = acc1;
            *(float2*)&out[(m0 + q) * 64 + c2 * 2] = o;
        }
    }
}

extern "C" void kernel_launch(void* const* d_in, const int* in_sizes, int n_in,
                              void* d_out, int out_size, void* d_ws, size_t ws_size,
                              hipStream_t stream) {
    const float* q_pts   = (const float*)d_in[0];
    const float* s_pts   = (const float*)d_in[1];
    const float* s_feats = (const float*)d_in[2];
    const int*   nb      = (const int*)d_in[3];
    const float* kpts    = (const float*)d_in[4];
    const float* W1      = (const float*)d_in[5];
    const float* gamma   = (const float*)d_in[6];
    const float* beta    = (const float*)d_in[7];
    const float* W2      = (const float*)d_in[8];
    const float* b2      = (const float*)d_in[9];
    float* out = (float*)d_out;

    float* ws = (float*)d_ws;
    float* bn = ws;                                        // 128 fp32
    unsigned short* w2b = (unsigned short*)(ws + 128);     // 61440 bf16 (122880 B)
    unsigned short* hst = w2b + 61440;                     // 50000*64 bf16 (6.4 MB)
    unsigned short* sfb = hst + N_PTS * CCH;               // 50000*64 bf16 (6.4 MB)
    float* sp4 = (float*)(sfb + N_PTS * CCH);              // 50000*4 fp32 (800 KB)
    float* kpc4 = sp4 + N_PTS * 4;                         // 15*4 fp32

    hipMemsetAsync(bn, 0, 128 * sizeof(float), stream);
    k_prep<<<STATS_BLOCKS + 30 + SP4_BLOCKS + 1, 256, 0, stream>>>(
        s_feats, W1, W2, s_pts, kpts, bn, hst, w2b, sfb, sp4, kpc4);
    k_main<<<N_PTS / QB, 256, 0, stream>>>(q_pts, sp4, sfb, nb, kpc4,
                                           gamma, beta, bn, b2, w2b, hst, out);
}